// Round 7
// baseline (357.665 us; speedup 1.0000x reference)
//
#include <hip/hip_runtime.h>
#include <stdint.h>
#include <math.h>

#define NB 4
#define NN 4096
#define NF 256
#define ND 128
#define QB 64            // q rows per attn block (4 waves x 16 rows)
#define KVB 32           // kv rows per tile
#define NR (NB * NN)

typedef __bf16 bf16x8 __attribute__((ext_vector_type(8)));
typedef float f32x4 __attribute__((ext_vector_type(4)));
typedef unsigned short u16x8 __attribute__((ext_vector_type(8)));
typedef unsigned short u16x4 __attribute__((ext_vector_type(4)));

__device__ __forceinline__ unsigned short f2bf(float f) {
    union { float f; uint32_t u; } v; v.f = f;
    uint32_t r = (v.u + 0x7FFFu + ((v.u >> 16) & 1u)) >> 16;
    return (unsigned short)r;
}

__device__ __forceinline__ bf16x8 lds_read16(const unsigned short* base, int byte_off) {
    return *reinterpret_cast<const bf16x8*>(reinterpret_cast<const char*>(base) + byte_off);
}

// ---------------- Kernel 1: QKV projection (bf16 MFMA, f32 acc) ----------------
// grid (256, 3): x = 64-row tile of B*N, y = projection (0=Q,1=K,2=V).
// Q pre-scaled by 1/sqrt(128). V written in B-frag tile order:
//   VS[b][tile(128)][chunk(4)][d(128)][m8] bf16  (tile=32 m-rows, chunk=8 m's)
__global__ __launch_bounds__(256) void qkv_proj(
    const float* __restrict__ h,
    const float* __restrict__ Wq, const float* __restrict__ bq,
    const float* __restrict__ Wk, const float* __restrict__ bk,
    const float* __restrict__ Wv, const float* __restrict__ bv,
    unsigned short* __restrict__ qo, unsigned short* __restrict__ ko,
    unsigned short* __restrict__ vs, float qscale)
{
    __shared__ unsigned short h_lds[64 * 128];
    __shared__ unsigned short w_lds[128 * 128];

    const int tid = threadIdx.x;
    const int lane = tid & 63;
    const int wv = tid >> 6;
    const int l15 = lane & 15;
    const int lhi = lane >> 4;
    const int R0 = blockIdx.x * 64;
    const int proj = blockIdx.y;

    const float* W    = proj == 0 ? Wq : (proj == 1 ? Wk : Wv);
    const float* bias = proj == 0 ? bq : (proj == 1 ? bk : bv);
    const float scale = proj == 0 ? qscale : 1.0f;

    f32x4 acc[8];
#pragma unroll
    for (int i = 0; i < 8; ++i) acc[i] = f32x4{0.f, 0.f, 0.f, 0.f};

    for (int kc = 0; kc < 2; ++kc) {
        const int c0 = kc * 128;
        __syncthreads();
#pragma unroll
        for (int p = 0; p < 8; ++p) {
            int idx = p * 256 + tid;
            int row = idx >> 5;
            int seg = idx & 31;
            f32x4 hv = *reinterpret_cast<const f32x4*>(h + (size_t)(R0 + row) * NF + c0 + seg * 4);
            u16x4 hb;
            hb[0] = f2bf(hv[0]); hb[1] = f2bf(hv[1]); hb[2] = f2bf(hv[2]); hb[3] = f2bf(hv[3]);
            int byte = (row * 256 + seg * 8) ^ ((row & 7) << 4);
            *reinterpret_cast<u16x4*>(reinterpret_cast<char*>(h_lds) + byte) = hb;
        }
#pragma unroll
        for (int p = 0; p < 16; ++p) {
            int idx = p * 256 + tid;
            int row = idx >> 5;
            int seg = idx & 31;
            f32x4 wv4 = *reinterpret_cast<const f32x4*>(W + (size_t)row * NF + c0 + seg * 4);
            u16x4 wb;
            wb[0] = f2bf(wv4[0]); wb[1] = f2bf(wv4[1]); wb[2] = f2bf(wv4[2]); wb[3] = f2bf(wv4[3]);
            int byte = (row * 256 + seg * 8) ^ ((row & 7) << 4);
            *reinterpret_cast<u16x4*>(reinterpret_cast<char*>(w_lds) + byte) = wb;
        }
        __syncthreads();
        const int arow = 16 * wv + l15;
#pragma unroll
        for (int ks = 0; ks < 4; ++ks) {
            int k = ks * 32 + 8 * lhi;
            bf16x8 a = lds_read16(h_lds, (arow * 256 + k * 2) ^ ((arow & 7) << 4));
#pragma unroll
            for (int cs = 0; cs < 8; ++cs) {
                int d = 16 * cs + l15;
                bf16x8 b = lds_read16(w_lds, (d * 256 + k * 2) ^ ((d & 7) << 4));
                acc[cs] = __builtin_amdgcn_mfma_f32_16x16x32_bf16(a, b, acc[cs], 0, 0, 0);
            }
        }
    }
    if (proj < 2) {
        unsigned short* out = proj == 0 ? qo : ko;
#pragma unroll
        for (int cs = 0; cs < 8; ++cs) {
            int d = 16 * cs + l15;
            float bb = bias[d];
#pragma unroll
            for (int j = 0; j < 4; ++j) {
                int row = R0 + 16 * wv + 4 * lhi + j;
                out[(size_t)row * ND + d] = f2bf((acc[cs][j] + bb) * scale);
            }
        }
    } else {
        // V in B-frag tile layout
        const int bb_ = R0 >> 12;
        const int nb_ = (R0 & (NN - 1)) + 16 * wv + 4 * lhi;
        const int pt = nb_ >> 5;
        const int ch = (nb_ >> 3) & 3;
        const int mm0 = nb_ & 7;
#pragma unroll
        for (int cs = 0; cs < 8; ++cs) {
            int d = 16 * cs + l15;
            float bb = bias[d];
            u16x4 o;
#pragma unroll
            for (int j = 0; j < 4; ++j) o[j] = f2bf(acc[cs][j] + bb);
            size_t idx = ((size_t)(bb_ * 128 + pt)) * 4096 + ch * 1024 + d * 8 + mm0;
            *reinterpret_cast<u16x4*>(vs + idx) = o;
        }
    }
}

// ---------------- Kernel 2: barrier-free per-wave flash attention ----------------
// 256 threads = 4 INDEPENDENT waves; wave w owns 16 q rows. No __syncthreads,
// no LDS staging: K/V B-frags read directly from global (L2-resident per XCD;
// VS pre-tiled in exact B-frag order). LDS only for the per-wave 1KB P tile.
// Record-max vote (THR=0): m_run is the TRUE running max (p <= 1, record entry
// exactly 1.0 -- the numerics that passed rounds 1-5); the shfl tree + rescale
// runs only on tiles that set a new record.
__global__ __launch_bounds__(256, 4) void attn(
    const unsigned short* __restrict__ Q,   // [B*N,128] bf16, pre-scaled
    const unsigned short* __restrict__ K,   // [B*N,128] bf16
    const unsigned short* __restrict__ VS,  // tiled V (see proj)
    const int* __restrict__ adj,            // [B,N,N] i32
    float* __restrict__ out,                // split-0 partial O (and final out)
    float* __restrict__ opart1,             // splits 1.. partial O
    float* __restrict__ ml,                 // [nsplit][NR][2] f32 (m, l)
    int ntl)                                // tiles per split
{
    __shared__ unsigned short p_lds[4 * 512];   // per-wave 16x32 P tile, 1KB each

    const int tid = threadIdx.x;
    const int lane = tid & 63;
    const int w = tid >> 6;
    const int l15 = lane & 15;
    const int lhi = lane >> 4;

    // XCD decode: each XCD serves ONE batch (K/V 2MB fits its 4MB L2)
    const int flat = blockIdx.x;
    const int x = flat & 7;
    const int qt = (flat >> 3) & 63;
    const int s_ = flat >> 9;
    const int combo = x + 8 * s_;
    const int b = combo & 3;
    const int sp = combo >> 2;
    const int q0 = qt * QB + 16 * w;            // this wave's first q row
    const size_t bN = (size_t)b * NN;
    const int ptbase = sp * ntl;
    const int ptlast = ptbase + ntl - 1;

    const unsigned short* Kb = K + bN * ND;
    const unsigned short* Vbase = VS + (size_t)b * 128 * 4096;
    const int* adjb = adj + (size_t)b * NN * NN + (size_t)(q0 + 4 * lhi) * NN + l15;

    auto adj_load = [&](int (&ar)[8], int pt) {
        const int m0 = pt * KVB;
#pragma unroll
        for (int ms = 0; ms < 2; ++ms)
#pragma unroll
            for (int j = 0; j < 4; ++j)
                ar[ms * 4 + j] = adjb[(size_t)j * NN + m0 + ms * 16];
    };

    // Q A-fragments straight from global
    bf16x8 qf[4];
#pragma unroll
    for (int ks = 0; ks < 4; ++ks)
        qf[ks] = *reinterpret_cast<const bf16x8*>(Q + (bN + q0 + l15) * ND + ks * 32 + 8 * lhi);

    f32x4 acc_o[8];
#pragma unroll
    for (int i = 0; i < 8; ++i) acc_o[i] = f32x4{0.f, 0.f, 0.f, 0.f};
    float m_run[4], l_part[4];
#pragma unroll
    for (int j = 0; j < 4; ++j) { m_run[j] = -INFINITY; l_part[j] = 0.f; }

    auto iter = [&](const int (&ac)[8], int (&an)[8], int pt) {
        adj_load(an, pt < ptlast ? pt + 1 : pt);
        const int m0 = pt * KVB;

        // ---- S = Q K^T : K B-frags direct from L2
        f32x4 s0 = f32x4{0.f, 0.f, 0.f, 0.f}, s1 = f32x4{0.f, 0.f, 0.f, 0.f};
        __builtin_amdgcn_s_setprio(1);
#pragma unroll
        for (int ks = 0; ks < 4; ++ks) {
            bf16x8 b0 = *reinterpret_cast<const bf16x8*>(Kb + (size_t)(m0 + l15) * ND + ks * 32 + lhi * 8);
            s0 = __builtin_amdgcn_mfma_f32_16x16x32_bf16(qf[ks], b0, s0, 0, 0, 0);
        }
#pragma unroll
        for (int ks = 0; ks < 4; ++ks) {
            bf16x8 b1 = *reinterpret_cast<const bf16x8*>(Kb + (size_t)(m0 + 16 + l15) * ND + ks * 32 + lhi * 8);
            s1 = __builtin_amdgcn_mfma_f32_16x16x32_bf16(qf[ks], b1, s1, 0, 0, 0);
        }
        __builtin_amdgcn_s_setprio(0);

        // ---- mask
#pragma unroll
        for (int j = 0; j < 4; ++j) {
            if (ac[j] == 0)     s0[j] = -9e15f;
            if (ac[4 + j] == 0) s1[j] = -9e15f;
        }

        // ---- record-max online softmax: tree + rescale only on new records
        float dmax = -INFINITY;
#pragma unroll
        for (int j = 0; j < 4; ++j)
            dmax = fmaxf(dmax, fmaxf(s0[j] - m_run[j], s1[j] - m_run[j]));
        if (!__all(dmax <= 0.0f)) {
#pragma unroll
            for (int j = 0; j < 4; ++j) {
                float mxj = fmaxf(s0[j], s1[j]);
#pragma unroll
                for (int off = 1; off < 16; off <<= 1)
                    mxj = fmaxf(mxj, __shfl_xor(mxj, off, 64));
                float mnew = fmaxf(m_run[j], mxj);
                float c = __expf(m_run[j] - mnew);
                m_run[j] = mnew;
                l_part[j] *= c;
#pragma unroll
                for (int ds = 0; ds < 8; ++ds) acc_o[ds][j] *= c;
            }
        }
        unsigned short pb[8];
#pragma unroll
        for (int j = 0; j < 4; ++j) {
            float p0 = __expf(s0[j] - m_run[j]);
            float p1 = __expf(s1[j] - m_run[j]);
            l_part[j] += p0 + p1;
            pb[j] = f2bf(p0);
            pb[4 + j] = f2bf(p1);
        }

        // ---- P -> per-wave LDS tile (same-wave RAW, compiler-ordered)
#pragma unroll
        for (int ms = 0; ms < 2; ++ms)
#pragma unroll
            for (int j = 0; j < 4; ++j) {
                int r = 4 * lhi + j;
                int c = 16 * ms + l15;
                int byte = w * 1024 + ((r * 64 + c * 2) ^ ((r & 7) << 4));
                *reinterpret_cast<unsigned short*>(reinterpret_cast<char*>(p_lds) + byte) = pb[ms * 4 + j];
            }
        bf16x8 pa = lds_read16(p_lds, w * 1024 + ((l15 * 64 + lhi * 16) ^ ((l15 & 7) << 4)));

        // ---- PV: V B-frags direct from L2 (VS pre-tiled)
        const unsigned short* vsrc = Vbase + (size_t)pt * 4096 + lhi * 1024 + l15 * 8;
        __builtin_amdgcn_s_setprio(1);
#pragma unroll
        for (int ds = 0; ds < 8; ++ds) {
            bf16x8 vbf = *reinterpret_cast<const bf16x8*>(vsrc + ds * 128);
            acc_o[ds] = __builtin_amdgcn_mfma_f32_16x16x32_bf16(pa, vbf, acc_o[ds], 0, 0, 0);
        }
        __builtin_amdgcn_s_setprio(0);
    };

    int acur[8], anxt[8];
    adj_load(acur, ptbase);
    for (int t = 0; t < ntl; t += 2) {
        iter(acur, anxt, ptbase + t);
        iter(anxt, acur, ptbase + t + 1);
    }

    // ---- epilogue: cross-lane l reduction (deferred from the loop; linear=exact)
#pragma unroll
    for (int j = 0; j < 4; ++j) {
        float rs = l_part[j];
#pragma unroll
        for (int off = 1; off < 16; off <<= 1)
            rs += __shfl_xor(rs, off, 64);
        l_part[j] = rs;
    }

    // store partial O (unnormalized) + (m, l)
    float* op = (sp == 0) ? out : (opart1 + (size_t)(sp - 1) * NR * ND);
#pragma unroll
    for (int ds = 0; ds < 8; ++ds) {
        int d = 16 * ds + l15;
#pragma unroll
        for (int j = 0; j < 4; ++j) {
            int row = q0 + 4 * lhi + j;
            op[(bN + row) * ND + d] = acc_o[ds][j];
        }
    }
    if (l15 == 0) {
#pragma unroll
        for (int j = 0; j < 4; ++j) {
            size_t gr = bN + q0 + 4 * lhi + j;
            float2 v2 = make_float2(m_run[j], l_part[j]);
            *reinterpret_cast<float2*>(ml + ((size_t)sp * NR + gr) * 2) = v2;
        }
    }
}

// ---------------- Kernel 3: merge the KV-splits (in-place on out) ----------------
__global__ __launch_bounds__(256) void merge_splits(
    float* __restrict__ out, const float* __restrict__ opart1,
    const float* __restrict__ ml, int nsplit)
{
    int idx = blockIdx.x * 256 + threadIdx.x;   // 0 .. NR*32-1
    int row = idx >> 5;
    int d4 = (idx & 31) * 4;
    float mmax = ml[(size_t)row * 2];
    for (int sp = 1; sp < nsplit; ++sp)
        mmax = fmaxf(mmax, ml[((size_t)sp * NR + row) * 2]);
    f32x4 o0 = *reinterpret_cast<const f32x4*>(out + (size_t)row * ND + d4);
    float w0 = __expf(ml[(size_t)row * 2] - mmax);
    float lsum = ml[(size_t)row * 2 + 1] * w0;
    f32x4 acc;
#pragma unroll
    for (int j = 0; j < 4; ++j) acc[j] = o0[j] * w0;
    for (int sp = 1; sp < nsplit; ++sp) {
        float m_s = ml[((size_t)sp * NR + row) * 2];
        float l_s = ml[((size_t)sp * NR + row) * 2 + 1];
        float ws_ = __expf(m_s - mmax);
        f32x4 os = *reinterpret_cast<const f32x4*>(opart1 + ((size_t)(sp - 1) * NR + row) * ND + d4);
#pragma unroll
        for (int j = 0; j < 4; ++j) acc[j] += os[j] * ws_;
        lsum += l_s * ws_;
    }
    float inv = 1.0f / lsum;
    f32x4 r;
#pragma unroll
    for (int j = 0; j < 4; ++j) r[j] = acc[j] * inv;
    *reinterpret_cast<f32x4*>(out + (size_t)row * ND + d4) = r;
}

extern "C" void kernel_launch(void* const* d_in, const int* in_sizes, int n_in,
                              void* d_out, int out_size, void* d_ws, size_t ws_size,
                              hipStream_t stream) {
    const float* h  = (const float*)d_in[0];
    const int* adj  = (const int*)d_in[1];
    const float* Wq = (const float*)d_in[2];
    const float* bq = (const float*)d_in[3];
    const float* Wk = (const float*)d_in[4];
    const float* bk = (const float*)d_in[5];
    const float* Wv = (const float*)d_in[6];
    const float* bv = (const float*)d_in[7];
    float* out = (float*)d_out;

    const size_t qkv_elems = (size_t)NB * NN * ND;      // 2,097,152 bf16 each
    unsigned short* qws  = (unsigned short*)d_ws;
    unsigned short* kws  = qws + qkv_elems;
    unsigned short* vsws = kws + qkv_elems;
    float* opart1 = (float*)(vsws + qkv_elems);

    // nsplit=4 needs 12.58MB (qkv) + 3*8.39MB (partials) + 0.52MB (ml)
    const size_t need4 = 3 * qkv_elems * 2 + 3 * (size_t)NR * ND * 4 + 4 * (size_t)NR * 2 * 4;
    const int nsplit = (ws_size >= need4) ? 4 : 2;
    float* mlws = opart1 + (size_t)(nsplit - 1) * NR * ND;
    const int ntl = (NN / KVB) / nsplit;                // 32 or 64

    const float qscale = 0.08838834764831845f;  // 1/sqrt(128)

    qkv_proj<<<dim3(NB * NN / 64, 3), 256, 0, stream>>>(
        h, Wq, bq, Wk, bk, Wv, bv, qws, kws, vsws, qscale);
    attn<<<dim3(NB * (NN / QB) * nsplit), 256, 0, stream>>>(
        qws, kws, vsws, adj, out, opart1, mlws, ntl);
    merge_splits<<<dim3(NR * 32 / 256), 256, 0, stream>>>(out, opart1, mlws, nsplit);
}

// Round 8
// 201.829 us; speedup vs baseline: 1.7721x; 1.7721x over previous
//
#include <hip/hip_runtime.h>
#include <stdint.h>
#include <math.h>

#define NB 4
#define NN 4096
#define NF 256
#define ND 128
#define KVB 32
#define NR (NB * NN)
#define QKVE ((size_t)NR * ND)      // 2,097,152 elements

typedef __bf16 bf16x8 __attribute__((ext_vector_type(8)));
typedef float f32x4 __attribute__((ext_vector_type(4)));
typedef unsigned short u16x4 __attribute__((ext_vector_type(4)));

__device__ __forceinline__ unsigned short f2bf(float f) {
    union { float f; uint32_t u; } v; v.f = f;
    uint32_t r = (v.u + 0x7FFFu + ((v.u >> 16) & 1u)) >> 16;
    return (unsigned short)r;
}
__device__ __forceinline__ float bf2f(unsigned short u) {
    union { uint32_t u; float f; } v; v.u = (uint32_t)u << 16; return v.f;
}
__device__ __forceinline__ bf16x8 lds_read16(const unsigned short* base, int byte_off) {
    return *reinterpret_cast<const bf16x8*>(reinterpret_cast<const char*>(base) + byte_off);
}

// ---------------- Kernel 0: pack adj -> bitmask (1 bit per edge) ----------------
// grid 1024 x 256. Each wave packs 256 uint64 words (64 adj ints each) via
// __ballot; reads fully coalesced 256B/instr, 8 loads in flight.
__global__ __launch_bounds__(256) void pack_adj(
    const int* __restrict__ adj, unsigned long long* __restrict__ pm64)
{
    const int lane = threadIdx.x & 63;
    const int w = threadIdx.x >> 6;
    const size_t base = ((size_t)blockIdx.x * 4 + w) * 256;
    for (int o = 0; o < 32; ++o) {
        const size_t wb = base + o * 8;
        int v[8];
#pragma unroll
        for (int u = 0; u < 8; ++u)
            v[u] = adj[(wb + u) * 64 + lane];
        unsigned long long m[8];
#pragma unroll
        for (int u = 0; u < 8; ++u)
            m[u] = __ballot(v[u] != 0);
        if (lane == 0) {
#pragma unroll
            for (int u = 0; u < 8; u += 2) {
                ulonglong2 st; st.x = m[u]; st.y = m[u + 1];
                *reinterpret_cast<ulonglong2*>(pm64 + wb + u) = st;
            }
        }
    }
}

// ---------------- Kernel 1: QKV projection (unchanged, proven) ----------------
// V written in B-frag tile order: VS[b][tile(128)][chunk(4)][d(128)][m8]
__global__ __launch_bounds__(256) void qkv_proj(
    const float* __restrict__ h,
    const float* __restrict__ Wq, const float* __restrict__ bq,
    const float* __restrict__ Wk, const float* __restrict__ bk,
    const float* __restrict__ Wv, const float* __restrict__ bv,
    unsigned short* __restrict__ qo, unsigned short* __restrict__ ko,
    unsigned short* __restrict__ vs, float qscale)
{
    __shared__ unsigned short h_lds[64 * 128];
    __shared__ unsigned short w_lds[128 * 128];

    const int tid = threadIdx.x;
    const int lane = tid & 63;
    const int wv = tid >> 6;
    const int l15 = lane & 15;
    const int lhi = lane >> 4;
    const int R0 = blockIdx.x * 64;
    const int proj = blockIdx.y;

    const float* W    = proj == 0 ? Wq : (proj == 1 ? Wk : Wv);
    const float* bias = proj == 0 ? bq : (proj == 1 ? bk : bv);
    const float scale = proj == 0 ? qscale : 1.0f;

    f32x4 acc[8];
#pragma unroll
    for (int i = 0; i < 8; ++i) acc[i] = f32x4{0.f, 0.f, 0.f, 0.f};

    for (int kc = 0; kc < 2; ++kc) {
        const int c0 = kc * 128;
        __syncthreads();
#pragma unroll
        for (int p = 0; p < 8; ++p) {
            int idx = p * 256 + tid;
            int row = idx >> 5;
            int seg = idx & 31;
            f32x4 hv = *reinterpret_cast<const f32x4*>(h + (size_t)(R0 + row) * NF + c0 + seg * 4);
            u16x4 hb;
            hb[0] = f2bf(hv[0]); hb[1] = f2bf(hv[1]); hb[2] = f2bf(hv[2]); hb[3] = f2bf(hv[3]);
            int byte = (row * 256 + seg * 8) ^ ((row & 7) << 4);
            *reinterpret_cast<u16x4*>(reinterpret_cast<char*>(h_lds) + byte) = hb;
        }
#pragma unroll
        for (int p = 0; p < 16; ++p) {
            int idx = p * 256 + tid;
            int row = idx >> 5;
            int seg = idx & 31;
            f32x4 wv4 = *reinterpret_cast<const f32x4*>(W + (size_t)row * NF + c0 + seg * 4);
            u16x4 wb;
            wb[0] = f2bf(wv4[0]); wb[1] = f2bf(wv4[1]); wb[2] = f2bf(wv4[2]); wb[3] = f2bf(wv4[3]);
            int byte = (row * 256 + seg * 8) ^ ((row & 7) << 4);
            *reinterpret_cast<u16x4*>(reinterpret_cast<char*>(w_lds) + byte) = wb;
        }
        __syncthreads();
        const int arow = 16 * wv + l15;
#pragma unroll
        for (int ks = 0; ks < 4; ++ks) {
            int k = ks * 32 + 8 * lhi;
            bf16x8 a = lds_read16(h_lds, (arow * 256 + k * 2) ^ ((arow & 7) << 4));
#pragma unroll
            for (int cs = 0; cs < 8; ++cs) {
                int d = 16 * cs + l15;
                bf16x8 b = lds_read16(w_lds, (d * 256 + k * 2) ^ ((d & 7) << 4));
                acc[cs] = __builtin_amdgcn_mfma_f32_16x16x32_bf16(a, b, acc[cs], 0, 0, 0);
            }
        }
    }
    if (proj < 2) {
        unsigned short* out = proj == 0 ? qo : ko;
#pragma unroll
        for (int cs = 0; cs < 8; ++cs) {
            int d = 16 * cs + l15;
            float bb = bias[d];
#pragma unroll
            for (int j = 0; j < 4; ++j) {
                int row = R0 + 16 * wv + 4 * lhi + j;
                out[(size_t)row * ND + d] = f2bf((acc[cs][j] + bb) * scale);
            }
        }
    } else {
        const int bb_ = R0 >> 12;
        const int nb_ = (R0 & (NN - 1)) + 16 * wv + 4 * lhi;
        const int pt = nb_ >> 5;
        const int ch = (nb_ >> 3) & 3;
        const int mm0 = nb_ & 7;
#pragma unroll
        for (int cs = 0; cs < 8; ++cs) {
            int d = 16 * cs + l15;
            float bb = bias[d];
            u16x4 o;
#pragma unroll
            for (int j = 0; j < 4; ++j) o[j] = f2bf(acc[cs][j] + bb);
            size_t idx = ((size_t)(bb_ * 128 + pt)) * 4096 + ch * 1024 + d * 8 + mm0;
            *reinterpret_cast<u16x4*>(vs + idx) = o;
        }
    }
}

// ---------------- Kernel 2: barrier-free flash attention, 32 q-rows/wave ------
// 4 independent waves/block (no __syncthreads). K + pre-tiled V read direct
// from per-XCD L2. Mask = packed bits, prefetched 4 tiles deep. l accumulates
// the bf16-ROUNDED p so the denominator exactly matches PV's weights.
// launch_bounds (256,2): cap 256 regs — (256,4) spilled in rounds 4/7.
__global__ __launch_bounds__(256, 2) void attn(
    const unsigned short* __restrict__ Q,   // [B*N,128] bf16, pre-scaled
    const unsigned short* __restrict__ K,   // [B*N,128] bf16
    const unsigned short* __restrict__ VS,  // tiled V (see proj)
    const unsigned int* __restrict__ pm,    // [B*N][128] packed adj words
    float* __restrict__ out,                // split-0 partial O (and final out)
    float* __restrict__ opart1,             // splits 1.. partial O (f32)
    float* __restrict__ ml,                 // [nsplit][NR][2] (m, l)
    int ntl)                                // tiles per split (32 or 64)
{
    __shared__ unsigned short p_lds[4096];  // 4 waves x 2 groups x 1KB P tiles

    const int tid = threadIdx.x;
    const int lane = tid & 63;
    const int w = tid >> 6;
    const int l15 = lane & 15;
    const int lhi = lane >> 4;

    // decode: 8 combos per 256-block slab -> XCD gets one (b,sp) pair per slab
    const int flat = blockIdx.x;
    const int x = flat & 7;
    const int rest = flat >> 3;
    const int qt = rest & 31;
    const int s2 = rest >> 5;
    const int combo = x + 8 * s2;
    const int b = combo & 3;
    const int sp = combo >> 2;
    const int q0w = qt * 128 + w * 32;      // wave's first q row (in batch)
    const size_t bN = (size_t)b * NN;
    const int ptbase = sp * ntl;

    const unsigned short* Kb = K + bN * ND;
    const unsigned short* Vbase = VS + (size_t)b * 128 * 4096;
    const unsigned int* pmb = pm + (bN + (size_t)q0w) * 128;

    // Q fragments (2 groups x 16 rows)
    bf16x8 qf[2][4];
#pragma unroll
    for (int g = 0; g < 2; ++g)
#pragma unroll
        for (int ks = 0; ks < 4; ++ks)
            qf[g][ks] = *reinterpret_cast<const bf16x8*>(
                Q + (bN + q0w + g * 16 + l15) * ND + ks * 32 + 8 * lhi);

    f32x4 acc[2][8];
#pragma unroll
    for (int g = 0; g < 2; ++g)
#pragma unroll
        for (int i = 0; i < 8; ++i) acc[g][i] = f32x4{0.f, 0.f, 0.f, 0.f};
    float m_run[8], l_part[8];
#pragma unroll
    for (int i = 0; i < 8; ++i) { m_run[i] = -INFINITY; l_part[i] = 0.f; }

    uint4 mk[8], mk2[8];
    auto mload = [&](uint4 (&m)[8], int widx) {
#pragma unroll
        for (int g = 0; g < 2; ++g)
#pragma unroll
            for (int j = 0; j < 4; ++j)
                m[g * 4 + j] = *reinterpret_cast<const uint4*>(
                    pmb + (g * 16 + 4 * lhi + j) * 128 + widx);
    };

    auto iter = [&](int pt, const unsigned int (&mw)[8]) {
        const int m0 = pt * KVB;
        f32x4 s[2][2];
#pragma unroll
        for (int g = 0; g < 2; ++g)
#pragma unroll
            for (int ms = 0; ms < 2; ++ms) s[g][ms] = f32x4{0.f, 0.f, 0.f, 0.f};

        __builtin_amdgcn_s_setprio(1);
#pragma unroll
        for (int ms = 0; ms < 2; ++ms) {
            bf16x8 kf[4];
#pragma unroll
            for (int ks = 0; ks < 4; ++ks)
                kf[ks] = *reinterpret_cast<const bf16x8*>(
                    Kb + (size_t)(m0 + ms * 16 + l15) * ND + ks * 32 + lhi * 8);
#pragma unroll
            for (int g = 0; g < 2; ++g)
#pragma unroll
                for (int ks = 0; ks < 4; ++ks)
                    s[g][ms] = __builtin_amdgcn_mfma_f32_16x16x32_bf16(
                        qf[g][ks], kf[ks], s[g][ms], 0, 0, 0);
        }
        __builtin_amdgcn_s_setprio(0);

        // mask from packed bits: col (16*ms + l15) of this tile's word
#pragma unroll
        for (int g = 0; g < 2; ++g)
#pragma unroll
            for (int ms = 0; ms < 2; ++ms)
#pragma unroll
                for (int j = 0; j < 4; ++j)
                    if (!((mw[g * 4 + j] >> (l15 + ms * 16)) & 1u))
                        s[g][ms][j] = -9e15f;

        // record-max online softmax (tree+rescale only on new records; exact skip)
        float dmax = -INFINITY;
#pragma unroll
        for (int g = 0; g < 2; ++g)
#pragma unroll
            for (int ms = 0; ms < 2; ++ms)
#pragma unroll
                for (int j = 0; j < 4; ++j)
                    dmax = fmaxf(dmax, s[g][ms][j] - m_run[g * 4 + j]);
        if (!__all(dmax <= 0.0f)) {
#pragma unroll
            for (int g = 0; g < 2; ++g)
#pragma unroll
                for (int j = 0; j < 4; ++j) {
                    float mx = fmaxf(s[g][0][j], s[g][1][j]);
#pragma unroll
                    for (int off = 1; off < 16; off <<= 1)
                        mx = fmaxf(mx, __shfl_xor(mx, off, 64));
                    float mnew = fmaxf(m_run[g * 4 + j], mx);
                    float c = __expf(m_run[g * 4 + j] - mnew);
                    m_run[g * 4 + j] = mnew;
                    l_part[g * 4 + j] *= c;
#pragma unroll
                    for (int ds = 0; ds < 8; ++ds) acc[g][ds][j] *= c;
                }
        }

        // p -> bf16; l accumulates the ROUNDED p (matches PV weights exactly)
#pragma unroll
        for (int g = 0; g < 2; ++g)
#pragma unroll
            for (int ms = 0; ms < 2; ++ms)
#pragma unroll
                for (int j = 0; j < 4; ++j) {
                    float p = __expf(s[g][ms][j] - m_run[g * 4 + j]);
                    unsigned short us = f2bf(p);
                    l_part[g * 4 + j] += bf2f(us);
                    int r = 4 * lhi + j;
                    int c = 16 * ms + l15;
                    int byte = (w * 2 + g) * 1024 + ((r * 64 + c * 2) ^ ((r & 7) << 4));
                    *reinterpret_cast<unsigned short*>(
                        reinterpret_cast<char*>(p_lds) + byte) = us;
                }
        bf16x8 pa[2];
#pragma unroll
        for (int g = 0; g < 2; ++g)
            pa[g] = lds_read16(p_lds,
                (w * 2 + g) * 1024 + ((l15 * 64 + lhi * 16) ^ ((l15 & 7) << 4)));

        // PV: V B-frags direct from L2 (VS pre-tiled); V shared across groups
        const unsigned short* vsrc = Vbase + (size_t)pt * 4096 + lhi * 1024 + l15 * 8;
        __builtin_amdgcn_s_setprio(1);
#pragma unroll
        for (int ds = 0; ds < 8; ++ds) {
            bf16x8 vf = *reinterpret_cast<const bf16x8*>(vsrc + ds * 128);
#pragma unroll
            for (int g = 0; g < 2; ++g)
                acc[g][ds] = __builtin_amdgcn_mfma_f32_16x16x32_bf16(
                    pa[g], vf, acc[g][ds], 0, 0, 0);
        }
        __builtin_amdgcn_s_setprio(0);
    };

    mload(mk, ptbase);
    for (int t = 0; t < ntl; t += 4) {
        mload(mk2, ptbase + ((t + 4 < ntl) ? t + 4 : t));
        unsigned int mwa[8];
#pragma unroll
        for (int i = 0; i < 8; ++i) mwa[i] = mk[i].x;
        iter(ptbase + t, mwa);
#pragma unroll
        for (int i = 0; i < 8; ++i) mwa[i] = mk[i].y;
        iter(ptbase + t + 1, mwa);
#pragma unroll
        for (int i = 0; i < 8; ++i) mwa[i] = mk[i].z;
        iter(ptbase + t + 2, mwa);
#pragma unroll
        for (int i = 0; i < 8; ++i) mwa[i] = mk[i].w;
        iter(ptbase + t + 3, mwa);
#pragma unroll
        for (int i = 0; i < 8; ++i) mk[i] = mk2[i];
    }

    // epilogue: deferred cross-lane l reduction (linear sum -> exact)
#pragma unroll
    for (int i = 0; i < 8; ++i) {
        float rs = l_part[i];
#pragma unroll
        for (int off = 1; off < 16; off <<= 1)
            rs += __shfl_xor(rs, off, 64);
        l_part[i] = rs;
    }

    float* op = (sp == 0) ? out : (opart1 + (size_t)(sp - 1) * NR * ND);
#pragma unroll
    for (int g = 0; g < 2; ++g)
#pragma unroll
        for (int ds = 0; ds < 8; ++ds)
#pragma unroll
            for (int j = 0; j < 4; ++j) {
                int row = q0w + g * 16 + 4 * lhi + j;
                op[(bN + row) * ND + 16 * ds + l15] = acc[g][ds][j];
            }
    if (l15 == 0) {
#pragma unroll
        for (int g = 0; g < 2; ++g)
#pragma unroll
            for (int j = 0; j < 4; ++j) {
                size_t gr = bN + q0w + g * 16 + 4 * lhi + j;
                *reinterpret_cast<float2*>(ml + ((size_t)sp * NR + gr) * 2) =
                    make_float2(m_run[g * 4 + j], l_part[g * 4 + j]);
            }
    }
}

// ---------------- Kernel 3: merge the KV-splits (in-place on out) ----------------
__global__ __launch_bounds__(256) void merge_splits(
    float* __restrict__ out, const float* __restrict__ opart1,
    const float* __restrict__ ml, int nsplit)
{
    int idx = blockIdx.x * 256 + threadIdx.x;
    int row = idx >> 5;
    int d4 = (idx & 31) * 4;
    float mmax = ml[(size_t)row * 2];
    for (int sp = 1; sp < nsplit; ++sp)
        mmax = fmaxf(mmax, ml[((size_t)sp * NR + row) * 2]);
    f32x4 o0 = *reinterpret_cast<const f32x4*>(out + (size_t)row * ND + d4);
    float w0 = __expf(ml[(size_t)row * 2] - mmax);
    float lsum = ml[(size_t)row * 2 + 1] * w0;
    f32x4 acc;
#pragma unroll
    for (int j = 0; j < 4; ++j) acc[j] = o0[j] * w0;
    for (int sp = 1; sp < nsplit; ++sp) {
        float m_s = ml[((size_t)sp * NR + row) * 2];
        float l_s = ml[((size_t)sp * NR + row) * 2 + 1];
        float ws_ = __expf(m_s - mmax);
        f32x4 os = *reinterpret_cast<const f32x4*>(opart1 + ((size_t)(sp - 1) * NR + row) * ND + d4);
#pragma unroll
        for (int j = 0; j < 4; ++j) acc[j] += os[j] * ws_;
        lsum += l_s * ws_;
    }
    float inv = 1.0f / lsum;
    f32x4 r;
#pragma unroll
    for (int j = 0; j < 4; ++j) r[j] = acc[j] * inv;
    *reinterpret_cast<f32x4*>(out + (size_t)row * ND + d4) = r;
}

extern "C" void kernel_launch(void* const* d_in, const int* in_sizes, int n_in,
                              void* d_out, int out_size, void* d_ws, size_t ws_size,
                              hipStream_t stream) {
    const float* h  = (const float*)d_in[0];
    const int* adj  = (const int*)d_in[1];
    const float* Wq = (const float*)d_in[2];
    const float* bq = (const float*)d_in[3];
    const float* Wk = (const float*)d_in[4];
    const float* bk = (const float*)d_in[5];
    const float* Wv = (const float*)d_in[6];
    const float* bv = (const float*)d_in[7];
    float* out = (float*)d_out;

    unsigned short* qws  = (unsigned short*)d_ws;
    unsigned short* kws  = qws + QKVE;
    unsigned short* vsws = kws + QKVE;
    float* opart1 = (float*)(vsws + QKVE);

    const size_t pm_bytes = (size_t)NB * NN * (NN / 8);          // 8.39 MB
    const size_t need4 = 3 * QKVE * 2 + 3 * QKVE * 4 + 4 * (size_t)NR * 2 * 4 + pm_bytes;
    const int nsplit = (ws_size >= need4) ? 4 : 2;
    float* mlws = opart1 + (size_t)(nsplit - 1) * NR * ND;
    unsigned int* pmws = (unsigned int*)(mlws + (size_t)nsplit * NR * 2);
    const int ntl = (NN / KVB) / nsplit;                          // 32 or 64

    const float qscale = 0.08838834764831845f;  // 1/sqrt(128)

    pack_adj<<<dim3(1024), 256, 0, stream>>>(adj, (unsigned long long*)pmws);
    qkv_proj<<<dim3(NB * NN / 64, 3), 256, 0, stream>>>(
        h, Wq, bq, Wk, bk, Wv, bv, qws, kws, vsws, qscale);
    attn<<<dim3(32 * 4 * nsplit), 256, 0, stream>>>(
        qws, kws, vsws, pmws, out, opart1, mlws, ntl);
    merge_splits<<<dim3(NR * 32 / 256), 256, 0, stream>>>(out, opart1, mlws, nsplit);
}

// Round 9
// 175.639 us; speedup vs baseline: 2.0364x; 1.1491x over previous
//
#include <hip/hip_runtime.h>
#include <stdint.h>
#include <math.h>

#define NB 4
#define NN 4096
#define NF 256
#define ND 128
#define KVB 32
#define NR (NB * NN)
#define QKVE ((size_t)NR * ND)      // 2,097,152 elements

typedef __bf16 bf16x8 __attribute__((ext_vector_type(8)));
typedef float f32x4 __attribute__((ext_vector_type(4)));
typedef unsigned short u16x4 __attribute__((ext_vector_type(4)));

__device__ __forceinline__ unsigned short f2bf(float f) {
    union { float f; uint32_t u; } v; v.f = f;
    uint32_t r = (v.u + 0x7FFFu + ((v.u >> 16) & 1u)) >> 16;
    return (unsigned short)r;
}
__device__ __forceinline__ float bf2f(unsigned short u) {
    union { uint32_t u; float f; } v; v.u = (uint32_t)u << 16; return v.f;
}
__device__ __forceinline__ bf16x8 lds_read16(const unsigned short* base, int byte_off) {
    return *reinterpret_cast<const bf16x8*>(reinterpret_cast<const char*>(base) + byte_off);
}

// ---------------- Kernel 0: pack adj -> bitmask (1 bit per edge) ----------------
__global__ __launch_bounds__(256) void pack_adj(
    const int* __restrict__ adj, unsigned long long* __restrict__ pm64)
{
    const int lane = threadIdx.x & 63;
    const int w = threadIdx.x >> 6;
    const size_t base = ((size_t)blockIdx.x * 4 + w) * 256;
    for (int o = 0; o < 32; ++o) {
        const size_t wb = base + o * 8;
        int v[8];
#pragma unroll
        for (int u = 0; u < 8; ++u)
            v[u] = adj[(wb + u) * 64 + lane];
        unsigned long long m[8];
#pragma unroll
        for (int u = 0; u < 8; ++u)
            m[u] = __ballot(v[u] != 0);
        if (lane == 0) {
#pragma unroll
            for (int u = 0; u < 8; u += 2) {
                ulonglong2 st; st.x = m[u]; st.y = m[u + 1];
                *reinterpret_cast<ulonglong2*>(pm64 + wb + u) = st;
            }
        }
    }
}

// ---------------- Kernel 1: QKV projection (unchanged, proven) ----------------
// V written in B-frag tile order: VS[b][tile(128)][chunk(4)][d(128)][m8]
__global__ __launch_bounds__(256) void qkv_proj(
    const float* __restrict__ h,
    const float* __restrict__ Wq, const float* __restrict__ bq,
    const float* __restrict__ Wk, const float* __restrict__ bk,
    const float* __restrict__ Wv, const float* __restrict__ bv,
    unsigned short* __restrict__ qo, unsigned short* __restrict__ ko,
    unsigned short* __restrict__ vs, float qscale)
{
    __shared__ unsigned short h_lds[64 * 128];
    __shared__ unsigned short w_lds[128 * 128];

    const int tid = threadIdx.x;
    const int lane = tid & 63;
    const int wv = tid >> 6;
    const int l15 = lane & 15;
    const int lhi = lane >> 4;
    const int R0 = blockIdx.x * 64;
    const int proj = blockIdx.y;

    const float* W    = proj == 0 ? Wq : (proj == 1 ? Wk : Wv);
    const float* bias = proj == 0 ? bq : (proj == 1 ? bk : bv);
    const float scale = proj == 0 ? qscale : 1.0f;

    f32x4 acc[8];
#pragma unroll
    for (int i = 0; i < 8; ++i) acc[i] = f32x4{0.f, 0.f, 0.f, 0.f};

    for (int kc = 0; kc < 2; ++kc) {
        const int c0 = kc * 128;
        __syncthreads();
#pragma unroll
        for (int p = 0; p < 8; ++p) {
            int idx = p * 256 + tid;
            int row = idx >> 5;
            int seg = idx & 31;
            f32x4 hv = *reinterpret_cast<const f32x4*>(h + (size_t)(R0 + row) * NF + c0 + seg * 4);
            u16x4 hb;
            hb[0] = f2bf(hv[0]); hb[1] = f2bf(hv[1]); hb[2] = f2bf(hv[2]); hb[3] = f2bf(hv[3]);
            int byte = (row * 256 + seg * 8) ^ ((row & 7) << 4);
            *reinterpret_cast<u16x4*>(reinterpret_cast<char*>(h_lds) + byte) = hb;
        }
#pragma unroll
        for (int p = 0; p < 16; ++p) {
            int idx = p * 256 + tid;
            int row = idx >> 5;
            int seg = idx & 31;
            f32x4 wv4 = *reinterpret_cast<const f32x4*>(W + (size_t)row * NF + c0 + seg * 4);
            u16x4 wb;
            wb[0] = f2bf(wv4[0]); wb[1] = f2bf(wv4[1]); wb[2] = f2bf(wv4[2]); wb[3] = f2bf(wv4[3]);
            int byte = (row * 256 + seg * 8) ^ ((row & 7) << 4);
            *reinterpret_cast<u16x4*>(reinterpret_cast<char*>(w_lds) + byte) = wb;
        }
        __syncthreads();
        const int arow = 16 * wv + l15;
#pragma unroll
        for (int ks = 0; ks < 4; ++ks) {
            int k = ks * 32 + 8 * lhi;
            bf16x8 a = lds_read16(h_lds, (arow * 256 + k * 2) ^ ((arow & 7) << 4));
#pragma unroll
            for (int cs = 0; cs < 8; ++cs) {
                int d = 16 * cs + l15;
                bf16x8 b = lds_read16(w_lds, (d * 256 + k * 2) ^ ((d & 7) << 4));
                acc[cs] = __builtin_amdgcn_mfma_f32_16x16x32_bf16(a, b, acc[cs], 0, 0, 0);
            }
        }
    }
    if (proj < 2) {
        unsigned short* out = proj == 0 ? qo : ko;
#pragma unroll
        for (int cs = 0; cs < 8; ++cs) {
            int d = 16 * cs + l15;
            float bb = bias[d];
#pragma unroll
            for (int j = 0; j < 4; ++j) {
                int row = R0 + 16 * wv + 4 * lhi + j;
                out[(size_t)row * ND + d] = f2bf((acc[cs][j] + bb) * scale);
            }
        }
    } else {
        const int bb_ = R0 >> 12;
        const int nb_ = (R0 & (NN - 1)) + 16 * wv + 4 * lhi;
        const int pt = nb_ >> 5;
        const int ch = (nb_ >> 3) & 3;
        const int mm0 = nb_ & 7;
#pragma unroll
        for (int cs = 0; cs < 8; ++cs) {
            int d = 16 * cs + l15;
            float bb = bias[d];
            u16x4 o;
#pragma unroll
            for (int j = 0; j < 4; ++j) o[j] = f2bf(acc[cs][j] + bb);
            size_t idx = ((size_t)(bb_ * 128 + pt)) * 4096 + ch * 1024 + d * 8 + mm0;
            *reinterpret_cast<u16x4*>(vs + idx) = o;
        }
    }
}

// -------- Kernel 2: barrier-free flash attention, SWAPPED-OPERAND softmax ------
// S^T = mfma(K,Q): lane holds 8 S values of ONE q-row (q = l15 + 16g) ->
// row-max = 3 local fmax + 2 shfl_xor, every tile, branchless; c/l/m lane-local.
// O^T = mfma(V,P): same vf/pa register patterns, acc transposed; epilogue
// stores f32x4 along d. No __syncthreads; K/V direct from per-XCD L2.
__global__ __launch_bounds__(256, 2) void attn(
    const unsigned short* __restrict__ Q,   // [B*N,128] bf16, pre-scaled
    const unsigned short* __restrict__ K,   // [B*N,128] bf16
    const unsigned short* __restrict__ VS,  // tiled V (see proj)
    const unsigned int* __restrict__ pm,    // [B*N][128] packed adj words
    float* __restrict__ out,                // split-0 partial O (and final out)
    float* __restrict__ opart1,             // splits 1.. partial O (f32)
    float* __restrict__ ml,                 // [nsplit][NR][2] (m, l)
    int ntl)                                // tiles per split (32 or 64)
{
    __shared__ unsigned short p_lds[8 * 512];  // 4 waves x 2 groups x 1KB P^T tiles

    const int tid = threadIdx.x;
    const int lane = tid & 63;
    const int w = tid >> 6;
    const int l15 = lane & 15;
    const int lhi = lane >> 4;

    const int flat = blockIdx.x;
    const int x = flat & 7;
    const int rest = flat >> 3;
    const int qt = rest & 31;
    const int s2 = rest >> 5;
    const int combo = x + 8 * s2;
    const int b = combo & 3;
    const int sp = combo >> 2;
    const int q0w = qt * 128 + w * 32;      // wave's first q row (in batch)
    const size_t bN = (size_t)b * NN;
    const int ptbase = sp * ntl;

    const unsigned short* Kb = K + bN * ND;
    const unsigned short* Vbase = VS + (size_t)b * 128 * 4096;

    // Q B-fragments (2 groups x 16 q-rows); B[k][q=l15] = Q[q=l15][k=8lhi..]
    bf16x8 qf[2][4];
#pragma unroll
    for (int g = 0; g < 2; ++g)
#pragma unroll
        for (int ks = 0; ks < 4; ++ks)
            qf[g][ks] = *reinterpret_cast<const bf16x8*>(
                Q + (bN + q0w + g * 16 + l15) * ND + ks * 32 + 8 * lhi);

    // mask rows: this lane's q-rows
    const unsigned int* pmr0 = pm + (bN + (size_t)(q0w + l15)) * 128;
    const unsigned int* pmr1 = pm + (bN + (size_t)(q0w + 16 + l15)) * 128;

    f32x4 acc[2][8];
#pragma unroll
    for (int g = 0; g < 2; ++g)
#pragma unroll
        for (int i = 0; i < 8; ++i) acc[g][i] = f32x4{0.f, 0.f, 0.f, 0.f};
    float m_run[2] = {-INFINITY, -INFINITY};
    float l_part[2] = {0.f, 0.f};

    auto iter = [&](int pt, unsigned int mw0, unsigned int mw1) {
        const int m0 = pt * KVB;

        // ---- K A-frags: A[m=l15][k=8lhi..] (shared across g)
        bf16x8 kf[2][4];
#pragma unroll
        for (int ms = 0; ms < 2; ++ms)
#pragma unroll
            for (int ks = 0; ks < 4; ++ks)
                kf[ms][ks] = *reinterpret_cast<const bf16x8*>(
                    Kb + (size_t)(m0 + ms * 16 + l15) * ND + ks * 32 + lhi * 8);

        // ---- S^T = mfma(K, Q): lane holds S[q=l15+16g][m=16ms+4lhi+r]
        f32x4 s[2][2];
#pragma unroll
        for (int g = 0; g < 2; ++g)
#pragma unroll
            for (int ms = 0; ms < 2; ++ms) s[g][ms] = f32x4{0.f, 0.f, 0.f, 0.f};
        __builtin_amdgcn_s_setprio(1);
#pragma unroll
        for (int g = 0; g < 2; ++g)
#pragma unroll
            for (int ms = 0; ms < 2; ++ms)
#pragma unroll
                for (int ks = 0; ks < 4; ++ks)
                    s[g][ms] = __builtin_amdgcn_mfma_f32_16x16x32_bf16(
                        kf[ms][ks], qf[g][ks], s[g][ms], 0, 0, 0);
        __builtin_amdgcn_s_setprio(0);

        // ---- V A-frags: V[m=8lhi+e][d=16ds+l15] (issue early, shared across g)
        const unsigned short* vsrc = Vbase + (size_t)pt * 4096 + lhi * 1024 + l15 * 8;
        bf16x8 vf[8];
#pragma unroll
        for (int ds = 0; ds < 8; ++ds)
            vf[ds] = *reinterpret_cast<const bf16x8*>(vsrc + ds * 128);

        const unsigned int mw[2] = {mw0, mw1};
        bf16x8 pa[2];
#pragma unroll
        for (int g = 0; g < 2; ++g) {
            // mask: bit (16ms + 4lhi + r) of this q-row's word
#pragma unroll
            for (int ms = 0; ms < 2; ++ms)
#pragma unroll
                for (int r = 0; r < 4; ++r)
                    if (!((mw[g] >> (16 * ms + 4 * lhi + r)) & 1u))
                        s[g][ms][r] = -9e15f;
            // lane-local row max + 2-shfl cross-lhi reduce (branchless, every tile)
            float mx = fmaxf(fmaxf(fmaxf(s[g][0][0], s[g][0][1]), fmaxf(s[g][0][2], s[g][0][3])),
                             fmaxf(fmaxf(s[g][1][0], s[g][1][1]), fmaxf(s[g][1][2], s[g][1][3])));
            mx = fmaxf(mx, __shfl_xor(mx, 16, 64));
            mx = fmaxf(mx, __shfl_xor(mx, 32, 64));
            float mnew = fmaxf(m_run[g], mx);
            float c = __expf(m_run[g] - mnew);   // exactly 1.0 when no new record
            m_run[g] = mnew;
            l_part[g] *= c;
#pragma unroll
            for (int ds = 0; ds < 8; ++ds) acc[g][ds] *= c;
            // p (bf16-rounded; l matches PV weights exactly)
            u16x4 pb[2];
#pragma unroll
            for (int ms = 0; ms < 2; ++ms)
#pragma unroll
                for (int r = 0; r < 4; ++r) {
                    float p = __expf(s[g][ms][r] - mnew);
                    unsigned short us = f2bf(p);
                    l_part[g] += bf2f(us);
                    pb[ms][r] = us;
                }
            // P^T -> per-wave-group LDS [q=l15][m]: b64 writes, b128 read
            const int base = (w * 2 + g) * 1024 + l15 * 64;
#pragma unroll
            for (int ms = 0; ms < 2; ++ms)
                *reinterpret_cast<u16x4*>(reinterpret_cast<char*>(p_lds)
                    + base + ms * 32 + lhi * 8) = pb[ms];
            pa[g] = lds_read16(p_lds, base + lhi * 16);  // P[q=l15][m=8lhi..]
        }

        // ---- O^T += mfma(V, P): acc[g][ds][r] = O[q=l15+16g][d=16ds+4lhi+r]
        __builtin_amdgcn_s_setprio(1);
#pragma unroll
        for (int ds = 0; ds < 8; ++ds)
#pragma unroll
            for (int g = 0; g < 2; ++g)
                acc[g][ds] = __builtin_amdgcn_mfma_f32_16x16x32_bf16(
                    vf[ds], pa[g], acc[g][ds], 0, 0, 0);
        __builtin_amdgcn_s_setprio(0);
    };

    // mask words prefetched 4 tiles deep (uint4 per row)
    uint4 mk[2], mk2[2];
    mk[0] = *reinterpret_cast<const uint4*>(pmr0 + ptbase);
    mk[1] = *reinterpret_cast<const uint4*>(pmr1 + ptbase);
    for (int t = 0; t < ntl; t += 4) {
        int tn = (t + 4 < ntl) ? t + 4 : t;
        mk2[0] = *reinterpret_cast<const uint4*>(pmr0 + ptbase + tn);
        mk2[1] = *reinterpret_cast<const uint4*>(pmr1 + ptbase + tn);
        iter(ptbase + t,     mk[0].x, mk[1].x);
        iter(ptbase + t + 1, mk[0].y, mk[1].y);
        iter(ptbase + t + 2, mk[0].z, mk[1].z);
        iter(ptbase + t + 3, mk[0].w, mk[1].w);
        mk[0] = mk2[0]; mk[1] = mk2[1];
    }

    // ---- epilogue: deferred cross-lhi l reduction (2 shfls, linear=exact)
#pragma unroll
    for (int g = 0; g < 2; ++g) {
        float rs = l_part[g];
        rs += __shfl_xor(rs, 16, 64);
        rs += __shfl_xor(rs, 32, 64);
        l_part[g] = rs;
    }

    float* op = (sp == 0) ? out : (opart1 + (size_t)(sp - 1) * NR * ND);
#pragma unroll
    for (int g = 0; g < 2; ++g) {
        const size_t rowbase = (bN + q0w + g * 16 + l15) * ND;
#pragma unroll
        for (int ds = 0; ds < 8; ++ds)
            *reinterpret_cast<f32x4*>(op + rowbase + 16 * ds + 4 * lhi) = acc[g][ds];
    }
    if (lhi == 0) {
#pragma unroll
        for (int g = 0; g < 2; ++g) {
            size_t gr = bN + q0w + g * 16 + l15;
            *reinterpret_cast<float2*>(ml + ((size_t)sp * NR + gr) * 2) =
                make_float2(m_run[g], l_part[g]);
        }
    }
}

// ---------------- Kernel 3: merge the KV-splits (in-place on out) ----------------
__global__ __launch_bounds__(256) void merge_splits(
    float* __restrict__ out, const float* __restrict__ opart1,
    const float* __restrict__ ml, int nsplit)
{
    int idx = blockIdx.x * 256 + threadIdx.x;
    int row = idx >> 5;
    int d4 = (idx & 31) * 4;
    float mmax = ml[(size_t)row * 2];
    for (int sp = 1; sp < nsplit; ++sp)
        mmax = fmaxf(mmax, ml[((size_t)sp * NR + row) * 2]);
    f32x4 o0 = *reinterpret_cast<const f32x4*>(out + (size_t)row * ND + d4);
    float w0 = __expf(ml[(size_t)row * 2] - mmax);
    float lsum = ml[(size_t)row * 2 + 1] * w0;
    f32x4 acc;
#pragma unroll
    for (int j = 0; j < 4; ++j) acc[j] = o0[j] * w0;
    for (int sp = 1; sp < nsplit; ++sp) {
        float m_s = ml[((size_t)sp * NR + row) * 2];
        float l_s = ml[((size_t)sp * NR + row) * 2 + 1];
        float ws_ = __expf(m_s - mmax);
        f32x4 os = *reinterpret_cast<const f32x4*>(opart1 + ((size_t)(sp - 1) * NR + row) * ND + d4);
#pragma unroll
        for (int j = 0; j < 4; ++j) acc[j] += os[j] * ws_;
        lsum += l_s * ws_;
    }
    float inv = 1.0f / lsum;
    f32x4 r;
#pragma unroll
    for (int j = 0; j < 4; ++j) r[j] = acc[j] * inv;
    *reinterpret_cast<f32x4*>(out + (size_t)row * ND + d4) = r;
}

extern "C" void kernel_launch(void* const* d_in, const int* in_sizes, int n_in,
                              void* d_out, int out_size, void* d_ws, size_t ws_size,
                              hipStream_t stream) {
    const float* h  = (const float*)d_in[0];
    const int* adj  = (const int*)d_in[1];
    const float* Wq = (const float*)d_in[2];
    const float* bq = (const float*)d_in[3];
    const float* Wk = (const float*)d_in[4];
    const float* bk = (const float*)d_in[5];
    const float* Wv = (const float*)d_in[6];
    const float* bv = (const float*)d_in[7];
    float* out = (float*)d_out;

    unsigned short* qws  = (unsigned short*)d_ws;
    unsigned short* kws  = qws + QKVE;
    unsigned short* vsws = kws + QKVE;
    float* opart1 = (float*)(vsws + QKVE);

    const size_t pm_bytes = (size_t)NB * NN * (NN / 8);          // 8.39 MB
    const size_t need4 = 3 * QKVE * 2 + 3 * QKVE * 4 + 4 * (size_t)NR * 2 * 4 + pm_bytes;
    const int nsplit = (ws_size >= need4) ? 4 : 2;
    float* mlws = opart1 + (size_t)(nsplit - 1) * NR * ND;
    unsigned int* pmws = (unsigned int*)(mlws + (size_t)nsplit * NR * 2);
    const int ntl = (NN / KVB) / nsplit;                          // 32 or 64

    const float qscale = 0.08838834764831845f;  // 1/sqrt(128)

    pack_adj<<<dim3(1024), 256, 0, stream>>>(adj, (unsigned long long*)pmws);
    qkv_proj<<<dim3(NB * NN / 64, 3), 256, 0, stream>>>(
        h, Wq, bq, Wk, bk, Wv, bv, qws, kws, vsws, qscale);
    attn<<<dim3(32 * 4 * nsplit), 256, 0, stream>>>(
        qws, kws, vsws, pmws, out, opart1, mlws, ntl);
    merge_splits<<<dim3(NR * 32 / 256), 256, 0, stream>>>(out, opart1, mlws, nsplit);
}

// Round 10
// 172.992 us; speedup vs baseline: 2.0675x; 1.0153x over previous
//
#include <hip/hip_runtime.h>
#include <stdint.h>
#include <math.h>

#define NB 4
#define NN 4096
#define NF 256
#define ND 128
#define KVB 32
#define NR (NB * NN)
#define QKVE ((size_t)NR * ND)      // 2,097,152 elements

typedef __bf16 bf16x8 __attribute__((ext_vector_type(8)));
typedef __bf16 bf16x4v __attribute__((ext_vector_type(4)));
typedef float f32x4 __attribute__((ext_vector_type(4)));
typedef unsigned short u16x4 __attribute__((ext_vector_type(4)));

__device__ __forceinline__ unsigned short f2bf(float f) {
    union { float f; uint32_t u; } v; v.f = f;
    uint32_t r = (v.u + 0x7FFFu + ((v.u >> 16) & 1u)) >> 16;
    return (unsigned short)r;
}
__device__ __forceinline__ bf16x8 lds_read16(const unsigned short* base, int byte_off) {
    return *reinterpret_cast<const bf16x8*>(reinterpret_cast<const char*>(base) + byte_off);
}

// ------- Kernel 0+1 fused: pack adj bitmask (blocks 0..1023) + QKV proj -------
// pack: reads adj fully coalesced, writes 1 bit/edge via __ballot.
// proj: V written in B-frag tile order VS[b][tile(128)][chunk(4)][d(128)][m8].
// Independent passes fused into one grid so the BW-bound pack overlaps the
// latency-bound proj (single-stream launches would serialize them).
__global__ __launch_bounds__(256) void pack_proj(
    const int* __restrict__ adj, unsigned long long* __restrict__ pm64,
    const float* __restrict__ h,
    const float* __restrict__ Wq, const float* __restrict__ bq,
    const float* __restrict__ Wk, const float* __restrict__ bk,
    const float* __restrict__ Wv, const float* __restrict__ bv,
    unsigned short* __restrict__ qo, unsigned short* __restrict__ ko,
    unsigned short* __restrict__ vs, float qscale)
{
    __shared__ unsigned short h_lds[64 * 128];
    __shared__ unsigned short w_lds[128 * 128];

    const int tid = threadIdx.x;
    const int lane = tid & 63;

    if (blockIdx.x < 1024) {
        // ---------------- pack path ----------------
        const int w = tid >> 6;
        const size_t base = ((size_t)blockIdx.x * 4 + w) * 256;
        for (int o = 0; o < 32; ++o) {
            const size_t wb = base + o * 8;
            int v[8];
#pragma unroll
            for (int u = 0; u < 8; ++u)
                v[u] = adj[(wb + u) * 64 + lane];
            unsigned long long m[8];
#pragma unroll
            for (int u = 0; u < 8; ++u)
                m[u] = __ballot(v[u] != 0);
            if (lane == 0) {
#pragma unroll
                for (int u = 0; u < 8; u += 2) {
                    ulonglong2 st; st.x = m[u]; st.y = m[u + 1];
                    *reinterpret_cast<ulonglong2*>(pm64 + wb + u) = st;
                }
            }
        }
        return;
    }

    // ---------------- proj path ----------------
    const int idx = blockIdx.x - 1024;
    const int proj = idx >> 8;          // 0=Q,1=K,2=V
    const int R0 = (idx & 255) * 64;
    const int wv = tid >> 6;
    const int l15 = lane & 15;
    const int lhi = lane >> 4;

    const float* W    = proj == 0 ? Wq : (proj == 1 ? Wk : Wv);
    const float* bias = proj == 0 ? bq : (proj == 1 ? bk : bv);
    const float scale = proj == 0 ? qscale : 1.0f;

    f32x4 acc[8];
#pragma unroll
    for (int i = 0; i < 8; ++i) acc[i] = f32x4{0.f, 0.f, 0.f, 0.f};

    for (int kc = 0; kc < 2; ++kc) {
        const int c0 = kc * 128;
        __syncthreads();
#pragma unroll
        for (int p = 0; p < 8; ++p) {
            int i2 = p * 256 + tid;
            int row = i2 >> 5;
            int seg = i2 & 31;
            f32x4 hv = *reinterpret_cast<const f32x4*>(h + (size_t)(R0 + row) * NF + c0 + seg * 4);
            u16x4 hb;
            hb[0] = f2bf(hv[0]); hb[1] = f2bf(hv[1]); hb[2] = f2bf(hv[2]); hb[3] = f2bf(hv[3]);
            int byte = (row * 256 + seg * 8) ^ ((row & 7) << 4);
            *reinterpret_cast<u16x4*>(reinterpret_cast<char*>(h_lds) + byte) = hb;
        }
#pragma unroll
        for (int p = 0; p < 16; ++p) {
            int i2 = p * 256 + tid;
            int row = i2 >> 5;
            int seg = i2 & 31;
            f32x4 wv4 = *reinterpret_cast<const f32x4*>(W + (size_t)row * NF + c0 + seg * 4);
            u16x4 wb;
            wb[0] = f2bf(wv4[0]); wb[1] = f2bf(wv4[1]); wb[2] = f2bf(wv4[2]); wb[3] = f2bf(wv4[3]);
            int byte = (row * 256 + seg * 8) ^ ((row & 7) << 4);
            *reinterpret_cast<u16x4*>(reinterpret_cast<char*>(w_lds) + byte) = wb;
        }
        __syncthreads();
        const int arow = 16 * wv + l15;
#pragma unroll
        for (int ks = 0; ks < 4; ++ks) {
            int k = ks * 32 + 8 * lhi;
            bf16x8 a = lds_read16(h_lds, (arow * 256 + k * 2) ^ ((arow & 7) << 4));
#pragma unroll
            for (int cs = 0; cs < 8; ++cs) {
                int d = 16 * cs + l15;
                bf16x8 b = lds_read16(w_lds, (d * 256 + k * 2) ^ ((d & 7) << 4));
                acc[cs] = __builtin_amdgcn_mfma_f32_16x16x32_bf16(a, b, acc[cs], 0, 0, 0);
            }
        }
    }
    if (proj < 2) {
        unsigned short* out = proj == 0 ? qo : ko;
#pragma unroll
        for (int cs = 0; cs < 8; ++cs) {
            int d = 16 * cs + l15;
            float bb = bias[d];
#pragma unroll
            for (int j = 0; j < 4; ++j) {
                int row = R0 + 16 * wv + 4 * lhi + j;
                out[(size_t)row * ND + d] = f2bf((acc[cs][j] + bb) * scale);
            }
        }
    } else {
        const int bb_ = R0 >> 12;
        const int nb_ = (R0 & (NN - 1)) + 16 * wv + 4 * lhi;
        const int pt = nb_ >> 5;
        const int ch = (nb_ >> 3) & 3;
        const int mm0 = nb_ & 7;
#pragma unroll
        for (int cs = 0; cs < 8; ++cs) {
            int d = 16 * cs + l15;
            float bb = bias[d];
            u16x4 o;
#pragma unroll
            for (int j = 0; j < 4; ++j) o[j] = f2bf(acc[cs][j] + bb);
            size_t oidx = ((size_t)(bb_ * 128 + pt)) * 4096 + ch * 1024 + d * 8 + mm0;
            *reinterpret_cast<u16x4*>(vs + oidx) = o;
        }
    }
}

// -------- Kernel 2: barrier-free flash attention, swapped softmax + load rotation
// S^T = mfma(K,Q): lane-local softmax (3 fmax + 2 shfl). O^T = mfma(V,P).
// kf/vf are loop-carried: next tile's K issued right after QK^T (hidden under
// softmax+PV), next V issued after PV (hidden under next QK^T+softmax).
__global__ __launch_bounds__(256, 2) void attn(
    const unsigned short* __restrict__ Q,   // [B*N,128] bf16, pre-scaled
    const unsigned short* __restrict__ K,   // [B*N,128] bf16
    const unsigned short* __restrict__ VS,  // tiled V (see proj)
    const unsigned int* __restrict__ pm,    // [B*N][128] packed adj words
    float* __restrict__ out,                // split-0 partial O (and final out)
    float* __restrict__ opart1,             // splits 1.. partial O (f32)
    float* __restrict__ ml,                 // [nsplit][NR][2] (m, l)
    int ntl)                                // tiles per split (32 or 64)
{
    __shared__ unsigned short p_lds[8 * 512];  // 4 waves x 2 groups x 1KB P^T tiles

    const int tid = threadIdx.x;
    const int lane = tid & 63;
    const int w = tid >> 6;
    const int l15 = lane & 15;
    const int lhi = lane >> 4;

    const int flat = blockIdx.x;
    const int x = flat & 7;
    const int rest = flat >> 3;
    const int qt = rest & 31;
    const int s2 = rest >> 5;
    const int combo = x + 8 * s2;
    const int b = combo & 3;
    const int sp = combo >> 2;
    const int q0w = qt * 128 + w * 32;      // wave's first q row (in batch)
    const size_t bN = (size_t)b * NN;
    const int ptbase = sp * ntl;

    const unsigned short* Kb = K + bN * ND;
    const unsigned short* Vbase = VS + (size_t)b * 128 * 4096;

    // Q B-fragments (2 groups x 16 q-rows)
    bf16x8 qf[2][4];
#pragma unroll
    for (int g = 0; g < 2; ++g)
#pragma unroll
        for (int ks = 0; ks < 4; ++ks)
            qf[g][ks] = *reinterpret_cast<const bf16x8*>(
                Q + (bN + q0w + g * 16 + l15) * ND + ks * 32 + 8 * lhi);

    const unsigned int* pmr0 = pm + (bN + (size_t)(q0w + l15)) * 128;
    const unsigned int* pmr1 = pm + (bN + (size_t)(q0w + 16 + l15)) * 128;

    f32x4 acc[2][8];
#pragma unroll
    for (int g = 0; g < 2; ++g)
#pragma unroll
        for (int i = 0; i < 8; ++i) acc[g][i] = f32x4{0.f, 0.f, 0.f, 0.f};
    float m_run[2] = {-INFINITY, -INFINITY};
    float l_part[2] = {0.f, 0.f};

    // loop-carried K/V fragments (load rotation)
    bf16x8 kf[2][4], vf[8];
    auto load_kf = [&](int pt) {
        const int m0 = pt * KVB;
#pragma unroll
        for (int ms = 0; ms < 2; ++ms)
#pragma unroll
            for (int ks = 0; ks < 4; ++ks)
                kf[ms][ks] = *reinterpret_cast<const bf16x8*>(
                    Kb + (size_t)(m0 + ms * 16 + l15) * ND + ks * 32 + lhi * 8);
    };
    auto load_vf = [&](int pt) {
        const unsigned short* vsrc = Vbase + (size_t)pt * 4096 + lhi * 1024 + l15 * 8;
#pragma unroll
        for (int ds = 0; ds < 8; ++ds)
            vf[ds] = *reinterpret_cast<const bf16x8*>(vsrc + ds * 128);
    };
    load_kf(ptbase);
    load_vf(ptbase);

    auto iter = [&](int ptn, unsigned int mw0, unsigned int mw1) {
        // ---- S^T = mfma(K, Q) from current kf
        f32x4 s[2][2];
#pragma unroll
        for (int g = 0; g < 2; ++g)
#pragma unroll
            for (int ms = 0; ms < 2; ++ms) s[g][ms] = f32x4{0.f, 0.f, 0.f, 0.f};
        __builtin_amdgcn_s_setprio(1);
#pragma unroll
        for (int g = 0; g < 2; ++g)
#pragma unroll
            for (int ms = 0; ms < 2; ++ms)
#pragma unroll
                for (int ks = 0; ks < 4; ++ks)
                    s[g][ms] = __builtin_amdgcn_mfma_f32_16x16x32_bf16(
                        kf[ms][ks], qf[g][ks], s[g][ms], 0, 0, 0);
        __builtin_amdgcn_s_setprio(0);

        // ---- prefetch NEXT tile's K now (latency hides under softmax+PV)
        load_kf(ptn);

        const unsigned int mw[2] = {mw0, mw1};
        bf16x8 pa[2];
#pragma unroll
        for (int g = 0; g < 2; ++g) {
#pragma unroll
            for (int ms = 0; ms < 2; ++ms)
#pragma unroll
                for (int r = 0; r < 4; ++r)
                    if (!((mw[g] >> (16 * ms + 4 * lhi + r)) & 1u))
                        s[g][ms][r] = -9e15f;
            // lane-local row max + 2 shfls (branchless, every tile)
            float mx = fmaxf(fmaxf(fmaxf(s[g][0][0], s[g][0][1]), fmaxf(s[g][0][2], s[g][0][3])),
                             fmaxf(fmaxf(s[g][1][0], s[g][1][1]), fmaxf(s[g][1][2], s[g][1][3])));
            mx = fmaxf(mx, __shfl_xor(mx, 16, 64));
            mx = fmaxf(mx, __shfl_xor(mx, 32, 64));
            float mnew = fmaxf(m_run[g], mx);
            float c = __expf(m_run[g] - mnew);   // exactly 1.0 when no new record
            m_run[g] = mnew;
            l_part[g] *= c;
#pragma unroll
            for (int ds = 0; ds < 8; ++ds) acc[g][ds] *= c;
            // p via native bf16 casts (compiler emits v_cvt_pk_bf16_f32);
            // l accumulates the ROUNDED p so denominator matches PV weights
            bf16x4v pbv[2];
#pragma unroll
            for (int ms = 0; ms < 2; ++ms)
#pragma unroll
                for (int r = 0; r < 4; ++r) {
                    float p = __expf(s[g][ms][r] - mnew);
                    __bf16 pb = (__bf16)p;
                    l_part[g] += (float)pb;
                    pbv[ms][r] = pb;
                }
            // P^T -> per-wave-group LDS [q=l15][m]: 2x b64 write, 1x b128 read
            const int base = (w * 2 + g) * 1024 + l15 * 64;
#pragma unroll
            for (int ms = 0; ms < 2; ++ms)
                *reinterpret_cast<bf16x4v*>(reinterpret_cast<char*>(p_lds)
                    + base + ms * 32 + lhi * 8) = pbv[ms];
            pa[g] = lds_read16(p_lds, base + lhi * 16);  // P[q=l15][m=8lhi..]
        }

        // ---- O^T += mfma(V, P) from current vf
        __builtin_amdgcn_s_setprio(1);
#pragma unroll
        for (int ds = 0; ds < 8; ++ds)
#pragma unroll
            for (int g = 0; g < 2; ++g)
                acc[g][ds] = __builtin_amdgcn_mfma_f32_16x16x32_bf16(
                    vf[ds], pa[g], acc[g][ds], 0, 0, 0);
        __builtin_amdgcn_s_setprio(0);

        // ---- prefetch NEXT tile's V (hides under next QK^T+softmax)
        load_vf(ptn);
    };

    // mask words prefetched 4 tiles deep (uint4 per row)
    uint4 mk[2], mk2[2];
    mk[0] = *reinterpret_cast<const uint4*>(pmr0 + ptbase);
    mk[1] = *reinterpret_cast<const uint4*>(pmr1 + ptbase);
    for (int t = 0; t < ntl; t += 4) {
        int tn4 = (t + 4 < ntl) ? t + 4 : t;
        mk2[0] = *reinterpret_cast<const uint4*>(pmr0 + ptbase + tn4);
        mk2[1] = *reinterpret_cast<const uint4*>(pmr1 + ptbase + tn4);
        iter(ptbase + t + 1, mk[0].x, mk[1].x);
        iter(ptbase + t + 2, mk[0].y, mk[1].y);
        iter(ptbase + t + 3, mk[0].z, mk[1].z);
        iter(ptbase + ((t + 4 < ntl) ? t + 4 : t + 3), mk[0].w, mk[1].w);
        mk[0] = mk2[0]; mk[1] = mk2[1];
    }

    // ---- epilogue: deferred cross-lhi l reduction (2 shfls, linear=exact)
#pragma unroll
    for (int g = 0; g < 2; ++g) {
        float rs = l_part[g];
        rs += __shfl_xor(rs, 16, 64);
        rs += __shfl_xor(rs, 32, 64);
        l_part[g] = rs;
    }

    float* op = (sp == 0) ? out : (opart1 + (size_t)(sp - 1) * NR * ND);
#pragma unroll
    for (int g = 0; g < 2; ++g) {
        const size_t rowbase = (bN + q0w + g * 16 + l15) * ND;
#pragma unroll
        for (int ds = 0; ds < 8; ++ds)
            *reinterpret_cast<f32x4*>(op + rowbase + 16 * ds + 4 * lhi) = acc[g][ds];
    }
    if (lhi == 0) {
#pragma unroll
        for (int g = 0; g < 2; ++g) {
            size_t gr = bN + q0w + g * 16 + l15;
            *reinterpret_cast<float2*>(ml + ((size_t)sp * NR + gr) * 2) =
                make_float2(m_run[g], l_part[g]);
        }
    }
}

// ---------------- Kernel 3: merge the KV-splits (in-place on out) ----------------
__global__ __launch_bounds__(256) void merge_splits(
    float* __restrict__ out, const float* __restrict__ opart1,
    const float* __restrict__ ml, int nsplit)
{
    int idx = blockIdx.x * 256 + threadIdx.x;
    int row = idx >> 5;
    int d4 = (idx & 31) * 4;
    float mmax = ml[(size_t)row * 2];
    for (int sp = 1; sp < nsplit; ++sp)
        mmax = fmaxf(mmax, ml[((size_t)sp * NR + row) * 2]);
    f32x4 o0 = *reinterpret_cast<const f32x4*>(out + (size_t)row * ND + d4);
    float w0 = __expf(ml[(size_t)row * 2] - mmax);
    float lsum = ml[(size_t)row * 2 + 1] * w0;
    f32x4 acc;
#pragma unroll
    for (int j = 0; j < 4; ++j) acc[j] = o0[j] * w0;
    for (int sp = 1; sp < nsplit; ++sp) {
        float m_s = ml[((size_t)sp * NR + row) * 2];
        float l_s = ml[((size_t)sp * NR + row) * 2 + 1];
        float ws_ = __expf(m_s - mmax);
        f32x4 os = *reinterpret_cast<const f32x4*>(opart1 + ((size_t)(sp - 1) * NR + row) * ND + d4);
#pragma unroll
        for (int j = 0; j < 4; ++j) acc[j] += os[j] * ws_;
        lsum += l_s * ws_;
    }
    float inv = 1.0f / lsum;
    f32x4 r;
#pragma unroll
    for (int j = 0; j < 4; ++j) r[j] = acc[j] * inv;
    *reinterpret_cast<f32x4*>(out + (size_t)row * ND + d4) = r;
}

extern "C" void kernel_launch(void* const* d_in, const int* in_sizes, int n_in,
                              void* d_out, int out_size, void* d_ws, size_t ws_size,
                              hipStream_t stream) {
    const float* h  = (const float*)d_in[0];
    const int* adj  = (const int*)d_in[1];
    const float* Wq = (const float*)d_in[2];
    const float* bq = (const float*)d_in[3];
    const float* Wk = (const float*)d_in[4];
    const float* bk = (const float*)d_in[5];
    const float* Wv = (const float*)d_in[6];
    const float* bv = (const float*)d_in[7];
    float* out = (float*)d_out;

    unsigned short* qws  = (unsigned short*)d_ws;
    unsigned short* kws  = qws + QKVE;
    unsigned short* vsws = kws + QKVE;
    float* opart1 = (float*)(vsws + QKVE);

    const size_t pm_bytes = (size_t)NB * NN * (NN / 8);          // 8.39 MB
    const size_t need4 = 3 * QKVE * 2 + 3 * QKVE * 4 + 4 * (size_t)NR * 2 * 4 + pm_bytes;
    const int nsplit = (ws_size >= need4) ? 4 : 2;
    float* mlws = opart1 + (size_t)(nsplit - 1) * NR * ND;
    unsigned int* pmws = (unsigned int*)(mlws + (size_t)nsplit * NR * 2);
    const int ntl = (NN / KVB) / nsplit;                          // 32 or 64

    const float qscale = 0.08838834764831845f;  // 1/sqrt(128)

    pack_proj<<<dim3(1024 + 768), 256, 0, stream>>>(
        adj, (unsigned long long*)pmws,
        h, Wq, bq, Wk, bk, Wv, bv, qws, kws, vsws, qscale);
    attn<<<dim3(32 * 4 * nsplit), 256, 0, stream>>>(
        qws, kws, vsws, pmws, out, opart1, mlws, ntl);
    merge_splits<<<dim3(NR * 32 / 256), 256, 0, stream>>>(out, opart1, mlws, nsplit);
}

// Round 11
// 172.987 us; speedup vs baseline: 2.0676x; 1.0000x over previous
//
#include <hip/hip_runtime.h>
#include <stdint.h>
#include <math.h>

#define NB 4
#define NN 4096
#define NF 256
#define ND 128
#define KVB 32
#define NR (NB * NN)
#define QKVE ((size_t)NR * ND)      // 2,097,152 elements

typedef __bf16 bf16x8 __attribute__((ext_vector_type(8)));
typedef __bf16 bf16x4v __attribute__((ext_vector_type(4)));
typedef float f32x4 __attribute__((ext_vector_type(4)));
typedef unsigned short u16x4 __attribute__((ext_vector_type(4)));

__device__ __forceinline__ unsigned short f2bf(float f) {
    union { float f; uint32_t u; } v; v.f = f;
    uint32_t r = (v.u + 0x7FFFu + ((v.u >> 16) & 1u)) >> 16;
    return (unsigned short)r;
}
__device__ __forceinline__ bf16x8 lds_read16(const unsigned short* base, int byte_off) {
    return *reinterpret_cast<const bf16x8*>(reinterpret_cast<const char*>(base) + byte_off);
}

// ------- Kernel 0+1 fused: pack adj bitmask (blocks 0..1023) + QKV proj -------
__global__ __launch_bounds__(256) void pack_proj(
    const int* __restrict__ adj, unsigned long long* __restrict__ pm64,
    const float* __restrict__ h,
    const float* __restrict__ Wq, const float* __restrict__ bq,
    const float* __restrict__ Wk, const float* __restrict__ bk,
    const float* __restrict__ Wv, const float* __restrict__ bv,
    unsigned short* __restrict__ qo, unsigned short* __restrict__ ko,
    unsigned short* __restrict__ vs, float qscale)
{
    __shared__ unsigned short h_lds[64 * 128];
    __shared__ unsigned short w_lds[128 * 128];

    const int tid = threadIdx.x;
    const int lane = tid & 63;

    if (blockIdx.x < 1024) {
        // ---------------- pack path ----------------
        const int w = tid >> 6;
        const size_t base = ((size_t)blockIdx.x * 4 + w) * 256;
        for (int o = 0; o < 32; ++o) {
            const size_t wb = base + o * 8;
            int v[8];
#pragma unroll
            for (int u = 0; u < 8; ++u)
                v[u] = adj[(wb + u) * 64 + lane];
            unsigned long long m[8];
#pragma unroll
            for (int u = 0; u < 8; ++u)
                m[u] = __ballot(v[u] != 0);
            if (lane == 0) {
#pragma unroll
                for (int u = 0; u < 8; u += 2) {
                    ulonglong2 st; st.x = m[u]; st.y = m[u + 1];
                    *reinterpret_cast<ulonglong2*>(pm64 + wb + u) = st;
                }
            }
        }
        return;
    }

    // ---------------- proj path ----------------
    const int idx = blockIdx.x - 1024;
    const int proj = idx >> 8;          // 0=Q,1=K,2=V
    const int R0 = (idx & 255) * 64;
    const int wv = tid >> 6;
    const int l15 = lane & 15;
    const int lhi = lane >> 4;

    const float* W    = proj == 0 ? Wq : (proj == 1 ? Wk : Wv);
    const float* bias = proj == 0 ? bq : (proj == 1 ? bk : bv);
    const float scale = proj == 0 ? qscale : 1.0f;

    f32x4 acc[8];
#pragma unroll
    for (int i = 0; i < 8; ++i) acc[i] = f32x4{0.f, 0.f, 0.f, 0.f};

    for (int kc = 0; kc < 2; ++kc) {
        const int c0 = kc * 128;
        __syncthreads();
#pragma unroll
        for (int p = 0; p < 8; ++p) {
            int i2 = p * 256 + tid;
            int row = i2 >> 5;
            int seg = i2 & 31;
            f32x4 hv = *reinterpret_cast<const f32x4*>(h + (size_t)(R0 + row) * NF + c0 + seg * 4);
            u16x4 hb;
            hb[0] = f2bf(hv[0]); hb[1] = f2bf(hv[1]); hb[2] = f2bf(hv[2]); hb[3] = f2bf(hv[3]);
            int byte = (row * 256 + seg * 8) ^ ((row & 7) << 4);
            *reinterpret_cast<u16x4*>(reinterpret_cast<char*>(h_lds) + byte) = hb;
        }
#pragma unroll
        for (int p = 0; p < 16; ++p) {
            int i2 = p * 256 + tid;
            int row = i2 >> 5;
            int seg = i2 & 31;
            f32x4 wv4 = *reinterpret_cast<const f32x4*>(W + (size_t)row * NF + c0 + seg * 4);
            u16x4 wb;
            wb[0] = f2bf(wv4[0]); wb[1] = f2bf(wv4[1]); wb[2] = f2bf(wv4[2]); wb[3] = f2bf(wv4[3]);
            int byte = (row * 256 + seg * 8) ^ ((row & 7) << 4);
            *reinterpret_cast<u16x4*>(reinterpret_cast<char*>(w_lds) + byte) = wb;
        }
        __syncthreads();
        const int arow = 16 * wv + l15;
#pragma unroll
        for (int ks = 0; ks < 4; ++ks) {
            int k = ks * 32 + 8 * lhi;
            bf16x8 a = lds_read16(h_lds, (arow * 256 + k * 2) ^ ((arow & 7) << 4));
#pragma unroll
            for (int cs = 0; cs < 8; ++cs) {
                int d = 16 * cs + l15;
                bf16x8 b = lds_read16(w_lds, (d * 256 + k * 2) ^ ((d & 7) << 4));
                acc[cs] = __builtin_amdgcn_mfma_f32_16x16x32_bf16(a, b, acc[cs], 0, 0, 0);
            }
        }
    }
    if (proj < 2) {
        unsigned short* out = proj == 0 ? qo : ko;
#pragma unroll
        for (int cs = 0; cs < 8; ++cs) {
            int d = 16 * cs + l15;
            float bb = bias[d];
#pragma unroll
            for (int j = 0; j < 4; ++j) {
                int row = R0 + 16 * wv + 4 * lhi + j;
                out[(size_t)row * ND + d] = f2bf((acc[cs][j] + bb) * scale);
            }
        }
    } else {
        const int bb_ = R0 >> 12;
        const int nb_ = (R0 & (NN - 1)) + 16 * wv + 4 * lhi;
        const int pt = nb_ >> 5;
        const int ch = (nb_ >> 3) & 3;
        const int mm0 = nb_ & 7;
#pragma unroll
        for (int cs = 0; cs < 8; ++cs) {
            int d = 16 * cs + l15;
            float bb = bias[d];
            u16x4 o;
#pragma unroll
            for (int j = 0; j < 4; ++j) o[j] = f2bf(acc[cs][j] + bb);
            size_t oidx = ((size_t)(bb_ * 128 + pt)) * 4096 + ch * 1024 + d * 8 + mm0;
            *reinterpret_cast<u16x4*>(vs + oidx) = o;
        }
    }
}

// -------- Kernel 2: barrier-free flash attention ------------------------------
// Swapped softmax (lane-local rows), log2 domain (scale folded into Q),
// DEFER-MAX THR=8 with bf16-rounded l (denominator == PV weights exactly),
// per-g PV interleave (PV(g=0) MFMAs overlap softmax(g=1) VALU),
// K/V load rotation. No barriers; K + pre-tiled V direct from per-XCD L2.
__global__ __launch_bounds__(256, 2) void attn(
    const unsigned short* __restrict__ Q,   // [B*N,128] bf16, scaled by 1/(sqrt(128)*ln2)
    const unsigned short* __restrict__ K,   // [B*N,128] bf16
    const unsigned short* __restrict__ VS,  // tiled V (see proj)
    const unsigned int* __restrict__ pm,    // [B*N][128] packed adj words
    float* __restrict__ out,                // split-0 partial O (and final out)
    float* __restrict__ opart1,             // splits 1.. partial O (f32)
    float* __restrict__ ml,                 // [nsplit][NR][2] (m, l) -- m in log2 units
    int ntl)                                // tiles per split (32 or 64)
{
    __shared__ unsigned short p_lds[8 * 512];  // 4 waves x 2 groups x 1KB P^T tiles

    const int tid = threadIdx.x;
    const int lane = tid & 63;
    const int w = tid >> 6;
    const int l15 = lane & 15;
    const int lhi = lane >> 4;

    const int flat = blockIdx.x;
    const int x = flat & 7;
    const int rest = flat >> 3;
    const int qt = rest & 31;
    const int s2 = rest >> 5;
    const int combo = x + 8 * s2;
    const int b = combo & 3;
    const int sp = combo >> 2;
    const int q0w = qt * 128 + w * 32;      // wave's first q row (in batch)
    const size_t bN = (size_t)b * NN;
    const int ptbase = sp * ntl;

    const unsigned short* Kb = K + bN * ND;
    const unsigned short* Vbase = VS + (size_t)b * 128 * 4096;

    bf16x8 qf[2][4];
#pragma unroll
    for (int g = 0; g < 2; ++g)
#pragma unroll
        for (int ks = 0; ks < 4; ++ks)
            qf[g][ks] = *reinterpret_cast<const bf16x8*>(
                Q + (bN + q0w + g * 16 + l15) * ND + ks * 32 + 8 * lhi);

    const unsigned int* pmr0 = pm + (bN + (size_t)(q0w + l15)) * 128;
    const unsigned int* pmr1 = pm + (bN + (size_t)(q0w + 16 + l15)) * 128;

    f32x4 acc[2][8];
#pragma unroll
    for (int g = 0; g < 2; ++g)
#pragma unroll
        for (int i = 0; i < 8; ++i) acc[g][i] = f32x4{0.f, 0.f, 0.f, 0.f};
    float m_run[2] = {-INFINITY, -INFINITY};
    float l_part[2] = {0.f, 0.f};

    // loop-carried K/V fragments (load rotation)
    bf16x8 kf[2][4], vf[8];
    auto load_kf = [&](int pt) {
        const int m0 = pt * KVB;
#pragma unroll
        for (int ms = 0; ms < 2; ++ms)
#pragma unroll
            for (int ks = 0; ks < 4; ++ks)
                kf[ms][ks] = *reinterpret_cast<const bf16x8*>(
                    Kb + (size_t)(m0 + ms * 16 + l15) * ND + ks * 32 + lhi * 8);
    };
    auto load_vf = [&](int pt) {
        const unsigned short* vsrc = Vbase + (size_t)pt * 4096 + lhi * 1024 + l15 * 8;
#pragma unroll
        for (int ds = 0; ds < 8; ++ds)
            vf[ds] = *reinterpret_cast<const bf16x8*>(vsrc + ds * 128);
    };
    load_kf(ptbase);
    load_vf(ptbase);

    auto iter = [&](int ptn, unsigned int mw0, unsigned int mw1) {
        // ---- S^T = mfma(K, Q) from current kf
        f32x4 s[2][2];
#pragma unroll
        for (int g = 0; g < 2; ++g)
#pragma unroll
            for (int ms = 0; ms < 2; ++ms) s[g][ms] = f32x4{0.f, 0.f, 0.f, 0.f};
        __builtin_amdgcn_s_setprio(1);
#pragma unroll
        for (int g = 0; g < 2; ++g)
#pragma unroll
            for (int ms = 0; ms < 2; ++ms)
#pragma unroll
                for (int ks = 0; ks < 4; ++ks)
                    s[g][ms] = __builtin_amdgcn_mfma_f32_16x16x32_bf16(
                        kf[ms][ks], qf[g][ks], s[g][ms], 0, 0, 0);
        __builtin_amdgcn_s_setprio(0);

        // ---- prefetch NEXT tile's K (hides under softmax+PV)
        load_kf(ptn);

        const unsigned int mw[2] = {mw0, mw1};
        // ---- mask + local max + defer-max vote (no shfl, no rescale common path)
        float smaxl[2];
        float dmax = -INFINITY;
#pragma unroll
        for (int g = 0; g < 2; ++g) {
            unsigned int mwg = mw[g] >> (4 * lhi);   // bit (16ms+r) now lane-invariant
#pragma unroll
            for (int ms = 0; ms < 2; ++ms)
#pragma unroll
                for (int r = 0; r < 4; ++r)
                    if (!((mwg >> (16 * ms + r)) & 1u)) s[g][ms][r] = -1.0e30f;
            float mx = fmaxf(fmaxf(fmaxf(s[g][0][0], s[g][0][1]), fmaxf(s[g][0][2], s[g][0][3])),
                             fmaxf(fmaxf(s[g][1][0], s[g][1][1]), fmaxf(s[g][1][2], s[g][1][3])));
            smaxl[g] = mx;
            dmax = fmaxf(dmax, mx - m_run[g]);
        }
        if (!__all(dmax <= 8.0f)) {        // rare after warm-up
#pragma unroll
            for (int g = 0; g < 2; ++g) {
                float mx = smaxl[g];
                mx = fmaxf(mx, __shfl_xor(mx, 16, 64));
                mx = fmaxf(mx, __shfl_xor(mx, 32, 64));
                float mnew = fmaxf(m_run[g], mx);
                float c = exp2f(m_run[g] - mnew);
                m_run[g] = mnew;
                l_part[g] *= c;
#pragma unroll
                for (int ds = 0; ds < 8; ++ds) acc[g][ds] *= c;
            }
        }

        // ---- per-g: p, P round-trip, PV (PV(g=0) overlaps softmax(g=1))
#pragma unroll
        for (int g = 0; g < 2; ++g) {
            bf16x4v pbv[2];
#pragma unroll
            for (int ms = 0; ms < 2; ++ms)
#pragma unroll
                for (int r = 0; r < 4; ++r) {
                    float p = exp2f(s[g][ms][r] - m_run[g]);   // p <= 2^8
                    __bf16 pb = (__bf16)p;
                    l_part[g] += (float)pb;    // l matches PV weights exactly
                    pbv[ms][r] = pb;
                }
            const int base = (w * 2 + g) * 1024 + l15 * 64;
#pragma unroll
            for (int ms = 0; ms < 2; ++ms)
                *reinterpret_cast<bf16x4v*>(reinterpret_cast<char*>(p_lds)
                    + base + ms * 32 + lhi * 8) = pbv[ms];
            bf16x8 pa = lds_read16(p_lds, base + lhi * 16);  // P[q=l15][m=8lhi..]
            __builtin_amdgcn_s_setprio(1);
#pragma unroll
            for (int ds = 0; ds < 8; ++ds)
                acc[g][ds] = __builtin_amdgcn_mfma_f32_16x16x32_bf16(
                    vf[ds], pa, acc[g][ds], 0, 0, 0);
            __builtin_amdgcn_s_setprio(0);
        }

        // ---- prefetch NEXT tile's V (vf shared by both g; reload after last use)
        load_vf(ptn);
    };

    // mask words prefetched 4 tiles deep (uint4 per row)
    uint4 mk[2], mk2[2];
    mk[0] = *reinterpret_cast<const uint4*>(pmr0 + ptbase);
    mk[1] = *reinterpret_cast<const uint4*>(pmr1 + ptbase);
    for (int t = 0; t < ntl; t += 4) {
        int tn4 = (t + 4 < ntl) ? t + 4 : t;
        mk2[0] = *reinterpret_cast<const uint4*>(pmr0 + ptbase + tn4);
        mk2[1] = *reinterpret_cast<const uint4*>(pmr1 + ptbase + tn4);
        iter(ptbase + t + 1, mk[0].x, mk[1].x);
        iter(ptbase + t + 2, mk[0].y, mk[1].y);
        iter(ptbase + t + 3, mk[0].z, mk[1].z);
        iter(ptbase + ((t + 4 < ntl) ? t + 4 : t + 3), mk[0].w, mk[1].w);
        mk[0] = mk2[0]; mk[1] = mk2[1];
    }

    // ---- epilogue: deferred cross-lhi l reduction (2 shfls, linear=exact)
#pragma unroll
    for (int g = 0; g < 2; ++g) {
        float rs = l_part[g];
        rs += __shfl_xor(rs, 16, 64);
        rs += __shfl_xor(rs, 32, 64);
        l_part[g] = rs;
    }

    float* op = (sp == 0) ? out : (opart1 + (size_t)(sp - 1) * NR * ND);
#pragma unroll
    for (int g = 0; g < 2; ++g) {
        const size_t rowbase = (bN + q0w + g * 16 + l15) * ND;
#pragma unroll
        for (int ds = 0; ds < 8; ++ds)
            *reinterpret_cast<f32x4*>(op + rowbase + 16 * ds + 4 * lhi) = acc[g][ds];
    }
    if (lhi == 0) {
#pragma unroll
        for (int g = 0; g < 2; ++g) {
            size_t gr = bN + q0w + g * 16 + l15;
            *reinterpret_cast<float2*>(ml + ((size_t)sp * NR + gr) * 2) =
                make_float2(m_run[g], l_part[g]);
        }
    }
}

// ---------------- Kernel 3: merge the KV-splits (m is log2-domain) -------------
__global__ __launch_bounds__(256) void merge_splits(
    float* __restrict__ out, const float* __restrict__ opart1,
    const float* __restrict__ ml, int nsplit)
{
    int idx = blockIdx.x * 256 + threadIdx.x;
    int row = idx >> 5;
    int d4 = (idx & 31) * 4;
    float mmax = ml[(size_t)row * 2];
    for (int sp = 1; sp < nsplit; ++sp)
        mmax = fmaxf(mmax, ml[((size_t)sp * NR + row) * 2]);
    f32x4 o0 = *reinterpret_cast<const f32x4*>(out + (size_t)row * ND + d4);
    float w0 = exp2f(ml[(size_t)row * 2] - mmax);
    float lsum = ml[(size_t)row * 2 + 1] * w0;
    f32x4 acc;
#pragma unroll
    for (int j = 0; j < 4; ++j) acc[j] = o0[j] * w0;
    for (int sp = 1; sp < nsplit; ++sp) {
        float m_s = ml[((size_t)sp * NR + row) * 2];
        float l_s = ml[((size_t)sp * NR + row) * 2 + 1];
        float ws_ = exp2f(m_s - mmax);
        f32x4 os = *reinterpret_cast<const f32x4*>(opart1 + ((size_t)(sp - 1) * NR + row) * ND + d4);
#pragma unroll
        for (int j = 0; j < 4; ++j) acc[j] += os[j] * ws_;
        lsum += l_s * ws_;
    }
    float inv = 1.0f / lsum;
    f32x4 r;
#pragma unroll
    for (int j = 0; j < 4; ++j) r[j] = acc[j] * inv;
    *reinterpret_cast<f32x4*>(out + (size_t)row * ND + d4) = r;
}

extern "C" void kernel_launch(void* const* d_in, const int* in_sizes, int n_in,
                              void* d_out, int out_size, void* d_ws, size_t ws_size,
                              hipStream_t stream) {
    const float* h  = (const float*)d_in[0];
    const int* adj  = (const int*)d_in[1];
    const float* Wq = (const float*)d_in[2];
    const float* bq = (const float*)d_in[3];
    const float* Wk = (const float*)d_in[4];
    const float* bk = (const float*)d_in[5];
    const float* Wv = (const float*)d_in[6];
    const float* bv = (const float*)d_in[7];
    float* out = (float*)d_out;

    unsigned short* qws  = (unsigned short*)d_ws;
    unsigned short* kws  = qws + QKVE;
    unsigned short* vsws = kws + QKVE;
    float* opart1 = (float*)(vsws + QKVE);

    const size_t pm_bytes = (size_t)NB * NN * (NN / 8);          // 8.39 MB
    const size_t need4 = 3 * QKVE * 2 + 3 * QKVE * 4 + 4 * (size_t)NR * 2 * 4 + pm_bytes;
    const int nsplit = (ws_size >= need4) ? 4 : 2;
    float* mlws = opart1 + (size_t)(nsplit - 1) * NR * ND;
    unsigned int* pmws = (unsigned int*)(mlws + (size_t)nsplit * NR * 2);
    const int ntl = (NN / KVB) / nsplit;                          // 32 or 64

    // 1/(sqrt(128) * ln2): scores land in log2 units -> exp2 softmax
    const float qscale = (float)(0.08838834764831845 / 0.6931471805599453);

    pack_proj<<<dim3(1024 + 768), 256, 0, stream>>>(
        adj, (unsigned long long*)pmws,
        h, Wq, bq, Wk, bk, Wv, bv, qws, kws, vsws, qscale);
    attn<<<dim3(32 * 4 * nsplit), 256, 0, stream>>>(
        qws, kws, vsws, pmws, out, opart1, mlws, ntl);
    merge_splits<<<dim3(NR * 32 / 256), 256, 0, stream>>>(out, opart1, mlws, nsplit);
}